// Round 3
// baseline (709.565 us; speedup 1.0000x reference)
//
#include <hip/hip_runtime.h>

// Problem constants (fixed shapes for this identifier)
#define N_ROWS 16384   // b*n = 4*4096
#define DIM    512
#define KCODES 8192

#define DECAYF 0.8f
#define RESIDF 0.2f
#define EPSF   1e-5f

// ---- d_out float offsets (outputs concatenated in return order) ----
#define OQ 0            // quantize_st    [16384,512]  (scratch: Xs fp16 h|l)
#define OI 8388608      // ind            [16384]
#define OL 8404992      // commit_loss    [1]
#define OE 8404993      // new_embed      [8192,512]   (scratch: Es fp16 h|l)
#define OC 12599297     // new_cluster    [8192]
#define OA 12607489     // new_embed_avg  [8192,512]   (scratch: dist top-2 partials)

// ---- workspace float offsets ----
#define WS_E2    0                  // [8192]
#define WS_BINS  8192               // [8192]
#define WS_LOSS  16384              // [1]
#define WS_TOTAL 16385              // [1]
#define WS_PI1   16400              // [4][16384] top-4 candidate idx (int, by merge)
#define WS_IND   (16400+65536)      // [16384] final idx (int)

typedef _Float16 half8 __attribute__((ext_vector_type(8)));
typedef float f32x4 __attribute__((ext_vector_type(4)));

__device__ __forceinline__ void ldg_lds16(const char* g, char* l) {
    __builtin_amdgcn_global_load_lds(
        (const __attribute__((address_space(1))) void*)g,
        (__attribute__((address_space(3))) void*)l, 16, 0, 0);
}

// monotonic (score,idx) -> u64: order-preserving, ties break to smaller idx
__device__ __forceinline__ unsigned long long enc64(float v, int idx) {
    unsigned int b = __float_as_uint(v);
    b ^= (unsigned)((int)b >> 31) | 0x80000000u;
    return ((unsigned long long)b << 13) | (unsigned)idx;
}

// ======= kernel 0a: split x (f32) -> Xs fp16 rows [512 h | 512 l] =======
__global__ void convx_kernel(const float* __restrict__ x, _Float16* __restrict__ xs) {
    int i = blockIdx.x * 256 + threadIdx.x;
    int row = i >> 6;
    int c8 = (i & 63) * 8;
    const float4* g = (const float4*)(x + row * DIM + c8);
    float4 v0 = g[0], v1 = g[1];
    float vv[8] = {v0.x, v0.y, v0.z, v0.w, v1.x, v1.y, v1.z, v1.w};
    half8 hv, lv;
#pragma unroll
    for (int j = 0; j < 8; ++j) {
        _Float16 h = (_Float16)vv[j];
        hv[j] = h;
        lv[j] = (_Float16)(vv[j] - (float)h);
    }
    *(half8*)(xs + row * 1024 + c8)       = hv;
    *(half8*)(xs + row * 1024 + 512 + c8) = lv;
}

// ======= kernel 0b: split embed (f32) -> Es fp16 rows [512 h | 512 l] =======
__global__ void conve_kernel(const float* __restrict__ e, _Float16* __restrict__ es) {
    int i = blockIdx.x * 256 + threadIdx.x;
    int row = i >> 6;
    int c8 = (i & 63) * 8;
    const float4* g = (const float4*)(e + row * DIM + c8);
    float4 v0 = g[0], v1 = g[1];
    float vv[8] = {v0.x, v0.y, v0.z, v0.w, v1.x, v1.y, v1.z, v1.w};
    half8 hv, lv;
#pragma unroll
    for (int j = 0; j < 8; ++j) {
        _Float16 h = (_Float16)vv[j];
        hv[j] = h;
        lv[j] = (_Float16)(vv[j] - (float)h);
    }
    *(half8*)(es + row * 1024 + c8)       = hv;
    *(half8*)(es + row * 1024 + 512 + c8) = lv;
}

// ================= kernel 1a: e2[k] = sum(embed[k]^2), f32 exact =================
__global__ void e2_kernel(const float* __restrict__ embed, float* __restrict__ ws) {
    int wid = threadIdx.x >> 6, lane = threadIdx.x & 63;
    int code = blockIdx.x * 4 + wid;
    const float4* row = (const float4*)(embed + code * DIM);
    float s = 0.f;
#pragma unroll
    for (int i = 0; i < 2; ++i) {
        float4 v = row[lane * 2 + i];
        s += v.x*v.x + v.y*v.y + v.z*v.z + v.w*v.w;
    }
#pragma unroll
    for (int off = 32; off; off >>= 1) s += __shfl_xor(s, off);
    if (lane == 0) ws[WS_E2 + code] = s;
}

// ============ kernel 1b: out_avg = 0.8 * embed_avg (runs AFTER merge consumed OA) ============
__global__ void avginit_kernel(const float* __restrict__ avg, float* __restrict__ out) {
    int i = blockIdx.x * blockDim.x + threadIdx.x;
    float4 v = ((const float4*)avg)[i];
    int base = i * 4;                              // OA region only 4B-aligned
    out[OA + base + 0] = DECAYF * v.x;
    out[OA + base + 1] = DECAYF * v.y;
    out[OA + base + 2] = DECAYF * v.z;
    out[OA + base + 3] = DECAYF * v.w;
}

// ============ kernel 2: 256x256 8-wave counted-vmcnt MFMA distance GEMM ============
// Grid 2048 = 64 row-tiles x 32 col-tiles; 512 thr = 8 waves (2M x 4N), wave tile 128x64.
// K = 16 steps of (32h|32l) fp16 = 128B/row. LDS: A/B double-buffered 4x32KB = 128KB.
// Steady state: vmcnt(8) = next K-step's 8 global_load_lds stay in flight across barriers.
// XOR swizzle byte^=((row&7)<<4), staging pre-swizzles the GLOBAL source (rule 21).
__global__ __launch_bounds__(512, 2) void dist_kernel(
        const _Float16* __restrict__ xs, const _Float16* __restrict__ es,
        const float* __restrict__ ws,
        unsigned long long* __restrict__ pt1, unsigned long long* __restrict__ pt2) {
    __shared__ __align__(16) char smem[131072];

    const int tid = threadIdx.x, wid = tid >> 6, lane = tid & 63;
    // XCD-bijective: xcd chunk owns 4 col-tiles (B slice 2MB -> L2-resident per XCD)
    const int i = blockIdx.x >> 3, xcd = blockIdx.x & 7;
    const int cb = xcd * 4 + (i >> 6);
    const int rb = i & 63;
    const int rowbase = rb * 256, colbase = cb * 256;

    const int wm = wid >> 2, wn = wid & 3;
    const int l15 = lane & 15, q = lane >> 4, l7 = lane & 7;

    int aoff[8], boff[4];
#pragma unroll
    for (int m = 0; m < 8; ++m)
        aoff[m] = (wm * 128 + m * 16 + l15) * 128 + ((q ^ l7) << 4);
#pragma unroll
    for (int n = 0; n < 4; ++n)
        boff[n] = (wn * 64 + n * 16 + l15) * 128 + ((q ^ l7) << 4);

    unsigned int gA[4], gB[4]; int ldst[4];
#pragma unroll
    for (int c = 0; c < 4; ++c) {
        int p = (c << 13) + (tid << 4);
        int r = p >> 7, b = p & 127;
        int lb = b ^ ((r & 7) << 4);
        unsigned sub = (unsigned)((lb >> 6) * 1024 + ((lb >> 4) & 3) * 16);
        gA[c] = (unsigned)(rowbase + r) * 2048u + sub;
        gB[c] = (unsigned)(colbase + r) * 2048u + sub;
        ldst[c] = (c << 13) + (wid << 10);
    }
    const char* xb = (const char*)xs;
    const char* eb = (const char*)es;

    f32x4 acc[8][4];
#pragma unroll
    for (int m = 0; m < 8; ++m)
#pragma unroll
        for (int n = 0; n < 4; ++n) acc[m][n] = (f32x4){0.f, 0.f, 0.f, 0.f};

#define STAGE(ks_, buf_) { _Pragma("unroll") \
    for (int c = 0; c < 4; ++c) { \
        ldg_lds16(xb + gA[c] + ((ks_) << 6), smem + ((buf_) << 15) + ldst[c]); \
        ldg_lds16(eb + gB[c] + ((ks_) << 6), smem + 65536 + ((buf_) << 15) + ldst[c]); \
    } }

    STAGE(0, 0);
    STAGE(1, 1);

#pragma unroll 2
    for (int ks = 0; ks < 16; ++ks) {
        if (ks == 15) { asm volatile("s_waitcnt vmcnt(0)" ::: "memory"); }
        else          { asm volatile("s_waitcnt vmcnt(8)" ::: "memory"); }
        __builtin_amdgcn_s_barrier();
        const char* Ab = smem + ((ks & 1) << 15);
        const char* Bb = smem + 65536 + ((ks & 1) << 15);
        half8 bh[4], bl[4];
#pragma unroll
        for (int n = 0; n < 4; ++n) {
            bh[n] = *(const half8*)(Bb + boff[n]);
            bl[n] = *(const half8*)(Bb + (boff[n] ^ 64));
        }
#pragma unroll
        for (int ph = 0; ph < 4; ++ph) {
            half8 ah0 = *(const half8*)(Ab + aoff[2*ph]);
            half8 al0 = *(const half8*)(Ab + (aoff[2*ph] ^ 64));
            half8 ah1 = *(const half8*)(Ab + aoff[2*ph+1]);
            half8 al1 = *(const half8*)(Ab + (aoff[2*ph+1] ^ 64));
            asm volatile("s_waitcnt lgkmcnt(0)" ::: "memory");
            __builtin_amdgcn_sched_barrier(0);
            __builtin_amdgcn_s_setprio(1);
#pragma unroll
            for (int n = 0; n < 4; ++n) {
                acc[2*ph][n] = __builtin_amdgcn_mfma_f32_16x16x32_f16(ah0, bh[n], acc[2*ph][n], 0, 0, 0);
                acc[2*ph][n] = __builtin_amdgcn_mfma_f32_16x16x32_f16(ah0, bl[n], acc[2*ph][n], 0, 0, 0);
                acc[2*ph][n] = __builtin_amdgcn_mfma_f32_16x16x32_f16(al0, bh[n], acc[2*ph][n], 0, 0, 0);
            }
#pragma unroll
            for (int n = 0; n < 4; ++n) {
                acc[2*ph+1][n] = __builtin_amdgcn_mfma_f32_16x16x32_f16(ah1, bh[n], acc[2*ph+1][n], 0, 0, 0);
                acc[2*ph+1][n] = __builtin_amdgcn_mfma_f32_16x16x32_f16(ah1, bl[n], acc[2*ph+1][n], 0, 0, 0);
                acc[2*ph+1][n] = __builtin_amdgcn_mfma_f32_16x16x32_f16(al1, bh[n], acc[2*ph+1][n], 0, 0, 0);
            }
            __builtin_amdgcn_s_setprio(0);
            __builtin_amdgcn_sched_barrier(0);
        }
        __builtin_amdgcn_s_barrier();
        if (ks < 14) STAGE(ks + 2, ks & 1);
    }
#undef STAGE

    // ---- epilogue: score = e2 - 2*dot, u64-packed top-2 per row of this 256-col tile ----
    const int cgbase = colbase + wn * 64 + l15;
    float e2v[4];
#pragma unroll
    for (int n = 0; n < 4; ++n) e2v[n] = ws[WS_E2 + cgbase + n * 16];

    unsigned long long* mbuf = (unsigned long long*)smem;  // [256 rows][4 wn][4 grp][2]
    const int grp = l15 >> 2;
    const bool wrt = (l15 & 3) == 0;
#pragma unroll
    for (int m = 0; m < 8; ++m) {
#pragma unroll
        for (int j = 0; j < 4; ++j) {
            unsigned long long u0 = enc64(fmaf(-2.f, acc[m][0][j], e2v[0]), cgbase);
            unsigned long long u1 = enc64(fmaf(-2.f, acc[m][1][j], e2v[1]), cgbase + 16);
            unsigned long long u2 = enc64(fmaf(-2.f, acc[m][2][j], e2v[2]), cgbase + 32);
            unsigned long long u3 = enc64(fmaf(-2.f, acc[m][3][j], e2v[3]), cgbase + 48);
            unsigned long long a1 = u0 < u1 ? u0 : u1, a2 = u0 < u1 ? u1 : u0;
            unsigned long long b1 = u2 < u3 ? u2 : u3, b2 = u2 < u3 ? u3 : u2;
            unsigned long long t1, t2;
            if (a1 <= b1) { t1 = a1; t2 = a2 < b1 ? a2 : b1; }
            else          { t1 = b1; t2 = b2 < a1 ? b2 : a1; }
#pragma unroll
            for (int mk = 1; mk <= 2; mk <<= 1) {
                unsigned long long o1 = __shfl_xor(t1, mk);
                unsigned long long o2 = __shfl_xor(t2, mk);
                if (o1 < t1) { t2 = t1 < o2 ? t1 : o2; t1 = o1; }
                else         { t2 = o1 < t2 ? o1 : t2; }
            }
            if (wrt) {
                int rl = wm * 128 + m * 16 + q * 4 + j;
                int base = ((rl * 4 + wn) * 4 + grp) * 2;
                mbuf[base] = t1; mbuf[base + 1] = t2;
            }
        }
    }
    __syncthreads();
    if (tid < 256) {
        const unsigned long long* rp = mbuf + tid * 32;
        unsigned long long t1 = ~0ull, t2 = ~0ull;
#pragma unroll
        for (int c = 0; c < 32; ++c) {
            unsigned long long v = rp[c];
            if (v < t1) { t2 = t1; t1 = v; }
            else if (v < t2) t2 = v;
        }
        pt1[cb * N_ROWS + rowbase + tid] = t1;
        pt2[cb * N_ROWS + rowbase + tid] = t2;
    }
}

// ====== kernel 2b: merge 32 col-block partials -> global top-4 candidate idx ======
__global__ void merge_kernel(const unsigned long long* __restrict__ pt1,
                             const unsigned long long* __restrict__ pt2,
                             float* __restrict__ ws) {
    int row = blockIdx.x * 256 + threadIdx.x;
    unsigned long long t[4] = {~0ull, ~0ull, ~0ull, ~0ull};
#pragma unroll 4
    for (int cb = 0; cb < 32; ++cb) {
        unsigned long long a = pt1[cb * N_ROWS + row];
        unsigned long long b = pt2[cb * N_ROWS + row];
#pragma unroll
        for (int z = 0; z < 2; ++z) {
            unsigned long long v = z ? b : a;
            if (v < t[3]) {
                t[3] = v;
                if (t[3] < t[2]) { unsigned long long x = t[2]; t[2] = t[3]; t[3] = x;
                    if (t[2] < t[1]) { x = t[1]; t[1] = t[2]; t[2] = x;
                        if (t[1] < t[0]) { x = t[0]; t[0] = t[1]; t[1] = x; } } }
            }
        }
    }
#pragma unroll
    for (int s = 0; s < 4; ++s)
        ((int*)ws)[WS_PI1 + s * N_ROWS + row] = (int)(t[s] & 0x1FFFu);
}

// ====== kernel 2c: fp64 refine of 4 candidates/row -> exact first-min argmin ======
__global__ void refine_kernel(const float* __restrict__ x, const float* __restrict__ embed,
                              float* __restrict__ ws, float* __restrict__ out) {
    int wid = threadIdx.x >> 6, lane = threadIdx.x & 63;
    int row = blockIdx.x * 4 + wid;
    const float* xr = x + row * DIM;
    double bestv = 1e300; int besti = 0x7fffffff;
#pragma unroll
    for (int s = 0; s < 4; ++s) {
        int ci = ((const int*)ws)[WS_PI1 + s * N_ROWS + row];
        const float* er = embed + ci * DIM;
        double d = 0.0;
#pragma unroll
        for (int u = 0; u < 8; ++u) {
            double diff = (double)xr[lane * 8 + u] - (double)er[lane * 8 + u];
            d += diff * diff;
        }
#pragma unroll
        for (int off = 32; off; off >>= 1) d += __shfl_xor(d, off);
        if (d < bestv || (d == bestv && ci < besti)) { bestv = d; besti = ci; }
    }
    if (lane == 0) {
        ((int*)ws)[WS_IND + row] = besti;
        out[OI + row] = (float)besti;
    }
}

// ===== kernel 3: gather quantize, commit-loss partial, scatter EMA sums =====
__global__ void gather_kernel(const float* __restrict__ x, const float* __restrict__ embed,
                              float* __restrict__ ws, float* __restrict__ out) {
    int tid = threadIdx.x;
    int rl  = tid >> 7;
    int c   = (tid & 127) * 4;
    int row = blockIdx.x * 2 + rl;
    int ind = ((const int*)ws)[WS_IND + row];
    float4 qv = *(const float4*)(embed + ind * DIM + c);
    float4 xv = *(const float4*)(x + row * DIM + c);
    float4 st;
    st.x = xv.x + (qv.x - xv.x); st.y = xv.y + (qv.y - xv.y);
    st.z = xv.z + (qv.z - xv.z); st.w = xv.w + (qv.w - xv.w);
    *(float4*)(out + OQ + row * DIM + c) = st;
    float dx = qv.x - xv.x, dy = qv.y - xv.y, dz = qv.z - xv.z, dw = qv.w - xv.w;
    float s = dx*dx + dy*dy + dz*dz + dw*dw;
#pragma unroll
    for (int off = 32; off; off >>= 1) s += __shfl_xor(s, off);
    __shared__ float ls[4];
    int wid = tid >> 6, lane = tid & 63;
    if (lane == 0) ls[wid] = s;
    __syncthreads();
    if (tid == 0) atomicAdd(ws + WS_LOSS, ls[0] + ls[1] + ls[2] + ls[3]);
    atomicAdd(out + OA + ind * DIM + c + 0, RESIDF * xv.x);
    atomicAdd(out + OA + ind * DIM + c + 1, RESIDF * xv.y);
    atomicAdd(out + OA + ind * DIM + c + 2, RESIDF * xv.z);
    atomicAdd(out + OA + ind * DIM + c + 3, RESIDF * xv.w);
    if ((tid & 127) == 0) atomicAdd(ws + WS_BINS + ind, 1.0f);
}

// ===== kernel 4: new_cluster_size, total reduction, finalize loss =====
__global__ void cluster_kernel(const float* __restrict__ cs, float* __restrict__ ws,
                               float* __restrict__ out) {
    int k = blockIdx.x * 256 + threadIdx.x;
    float ncs = DECAYF * cs[k] + RESIDF * ws[WS_BINS + k];
    out[OC + k] = ncs;
    float s = ncs;
#pragma unroll
    for (int off = 32; off; off >>= 1) s += __shfl_xor(s, off);
    __shared__ float ls[4];
    int wid = threadIdx.x >> 6, lane = threadIdx.x & 63;
    if (lane == 0) ls[wid] = s;
    __syncthreads();
    if (threadIdx.x == 0) atomicAdd(ws + WS_TOTAL, ls[0] + ls[1] + ls[2] + ls[3]);
    if (k == 0) out[OL] = ws[WS_LOSS] / 8388608.0f;
}

// ===== kernel 5: new_embed = new_embed_avg / laplace-smoothed cluster sizes =====
__global__ void finalize_kernel(const float* __restrict__ ws, float* __restrict__ out) {
    int i = blockIdx.x * 256 + threadIdx.x;
    int base = i * 4;
    int k = base >> 9;
    float total = ws[WS_TOTAL];
    float ncs = out[OC + k];
    float sm = (ncs + EPSF) / (total + (float)KCODES * EPSF) * total;
#pragma unroll
    for (int j = 0; j < 4; ++j) {
        float av = out[OA + base + j];
        out[OE + base + j] = av / sm;
    }
}

extern "C" void kernel_launch(void* const* d_in, const int* in_sizes, int n_in,
                              void* d_out, int out_size, void* d_ws, size_t ws_size,
                              hipStream_t stream) {
    const float* x     = (const float*)d_in[0];
    const float* embed = (const float*)d_in[1];
    const float* cs    = (const float*)d_in[2];
    const float* avg   = (const float*)d_in[3];
    float* out = (float*)d_out;
    float* ws  = (float*)d_ws;

    // fp16 scratch inside d_out (regions rewritten later in the pipeline):
    _Float16* xs = (_Float16*)((char*)d_out + (size_t)OQ * 4);
    _Float16* es = (_Float16*)((char*)d_out + (((size_t)OE * 4 + 15) & ~(size_t)15));
    // dist partials (8MB) in OA region; consumed by merge BEFORE avginit rewrites OA
    unsigned long long* pt1 =
        (unsigned long long*)((char*)d_out + (((size_t)OA * 4 + 15) & ~(size_t)15));
    unsigned long long* pt2 = pt1 + 32 * N_ROWS;

    hipMemsetAsync((char*)d_ws + WS_BINS * 4, 0, (8192 + 2) * 4, stream);

    convx_kernel  <<<4096, 256, 0, stream>>>(x, xs);
    conve_kernel  <<<2048, 256, 0, stream>>>(embed, es);
    e2_kernel     <<<KCODES / 4, 256, 0, stream>>>(embed, ws);
    dist_kernel   <<<2048, 512, 0, stream>>>(xs, es, ws, pt1, pt2);
    merge_kernel  <<<N_ROWS / 256, 256, 0, stream>>>(pt1, pt2, ws);
    refine_kernel <<<N_ROWS / 4, 256, 0, stream>>>(x, embed, ws, out);
    avginit_kernel<<<4096, 256, 0, stream>>>(avg, out);
    gather_kernel <<<N_ROWS / 2, 256, 0, stream>>>(x, embed, ws, out);
    cluster_kernel<<<KCODES / 256, 256, 0, stream>>>(cs, ws, out);
    finalize_kernel<<<4096, 256, 0, stream>>>(ws, out);
}

// Round 4
// 571.100 us; speedup vs baseline: 1.2425x; 1.2425x over previous
//
#include <hip/hip_runtime.h>

// Problem constants (fixed shapes for this identifier)
#define N_ROWS 16384   // b*n = 4*4096
#define DIM    512
#define KCODES 8192

#define DECAYF 0.8f
#define RESIDF 0.2f
#define EPSF   1e-5f
#define THRGAP 0.15f   // refine-skip threshold (~8 sigma of 1-pass fp16 score noise)

// ---- d_out float offsets (outputs concatenated in return order) ----
#define OQ 0            // quantize_st    [16384,512]  (scratch: Xs fp16)
#define OI 8388608      // ind            [16384]
#define OL 8404992      // commit_loss    [1]
#define OE 8404993      // new_embed      [8192,512]   (scratch: Es fp16 + pt1)
#define OC 12599297     // new_cluster    [8192]
#define OA 12607489     // new_embed_avg  [8192,512]   (scratch: pt2)

// ---- workspace float offsets ----
#define WS_E2    0                  // [8192]
#define WS_BINS  8192               // [8192]
#define WS_LOSS  16384              // [1]
#define WS_TOTAL 16385              // [1]
#define WS_PI1   16400              // [4][16384] top-4 candidate idx (int)
#define WS_GAP   (16400+65536)      // [16384] noisy top1-top2 gap

typedef _Float16 half8 __attribute__((ext_vector_type(8)));
typedef float f32x4 __attribute__((ext_vector_type(4)));

__device__ __forceinline__ void ldg_lds16(const char* g, char* l) {
    __builtin_amdgcn_global_load_lds(
        (const __attribute__((address_space(1))) void*)g,
        (__attribute__((address_space(3))) void*)l, 16, 0, 0);
}

// monotonic (score,idx) -> u64: order-preserving, ties break to smaller idx
__device__ __forceinline__ unsigned long long enc64(float v, int idx) {
    unsigned int b = __float_as_uint(v);
    b ^= (unsigned)((int)b >> 31) | 0x80000000u;
    return ((unsigned long long)b << 13) | (unsigned)idx;
}
__device__ __forceinline__ float dec64(unsigned long long u) {
    unsigned int eb = (unsigned int)(u >> 13);
    unsigned int b = (eb & 0x80000000u) ? (eb ^ 0x80000000u) : ~eb;
    return __uint_as_float(b);
}

// ======= kernel 0a: x (f32) -> Xs fp16 (h only) =======
__global__ void convx_kernel(const float* __restrict__ x, _Float16* __restrict__ xs) {
    int i = blockIdx.x * 256 + threadIdx.x;        // 1,048,576 threads, 8 elems each
    int row = i >> 6;
    int c8 = (i & 63) * 8;
    const float4* g = (const float4*)(x + row * DIM + c8);
    float4 v0 = g[0], v1 = g[1];
    float vv[8] = {v0.x, v0.y, v0.z, v0.w, v1.x, v1.y, v1.z, v1.w};
    half8 hv;
#pragma unroll
    for (int j = 0; j < 8; ++j) hv[j] = (_Float16)vv[j];
    *(half8*)(xs + row * DIM + c8) = hv;
}

// ======= kernel 0b: embed -> Es fp16 + e2[k] = sum(embed[k]^2) f32 (fused) =======
__global__ void conve_kernel(const float* __restrict__ e, _Float16* __restrict__ es,
                             float* __restrict__ ws) {
    int i = blockIdx.x * 256 + threadIdx.x;        // 524,288 threads; one wave per row
    int row = i >> 6;
    int lane = threadIdx.x & 63;
    int c8 = (i & 63) * 8;
    const float4* g = (const float4*)(e + row * DIM + c8);
    float4 v0 = g[0], v1 = g[1];
    float vv[8] = {v0.x, v0.y, v0.z, v0.w, v1.x, v1.y, v1.z, v1.w};
    half8 hv;
    float s = 0.f;
#pragma unroll
    for (int j = 0; j < 8; ++j) { hv[j] = (_Float16)vv[j]; s += vv[j] * vv[j]; }
    *(half8*)(es + row * DIM + c8) = hv;
#pragma unroll
    for (int off = 32; off; off >>= 1) s += __shfl_xor(s, off);
    if (lane == 0) ws[WS_E2 + row] = s;
}

// ============ kernel 1: out_avg = 0.8 * embed_avg (runs AFTER merge consumed pt2) ============
__global__ void avginit_kernel(const float* __restrict__ avg, float* __restrict__ out) {
    int i = blockIdx.x * blockDim.x + threadIdx.x;
    float4 v = ((const float4*)avg)[i];
    int base = i * 4;                              // OA region only 4B-aligned
    out[OA + base + 0] = DECAYF * v.x;
    out[OA + base + 1] = DECAYF * v.y;
    out[OA + base + 2] = DECAYF * v.z;
    out[OA + base + 3] = DECAYF * v.w;
}

// ============ kernel 2: 1-pass fp16 MFMA distance GEMM, 128x128 tile ============
// 4 waves (2x2, wave tile 64x64), BK=32 (64B/row), 16 K-steps, dbuf LDS 32KB ->
// 4 blocks/CU. Counted vmcnt(4): next K-step's 4 global_load_lds in flight across
// barriers. Swizzle (64B rows): slot = q ^ ((row>>1)&3); staging pre-swizzles the
// GLOBAL source, LDS stays linear (rule 21); verified 2-lane/bank (free).
__global__ __launch_bounds__(256, 4) void dist_kernel(
        const _Float16* __restrict__ xs, const _Float16* __restrict__ es,
        const float* __restrict__ ws,
        unsigned long long* __restrict__ pt1, unsigned long long* __restrict__ pt2) {
    __shared__ __align__(16) char smem[32768];   // A0|B0 at 0|8K, A1|B1 at 16K|24K

    const int tid = threadIdx.x, wid = tid >> 6, lane = tid & 63;
    // XCD-bijective remap (8192 blocks, 8 XCDs x 1024): each XCD owns 8 col-tiles;
    // row-tiles iterate fastest so the 128KB B-tile stays L2-resident per sweep.
    const int xcd = blockIdx.x & 7, i = blockIdx.x >> 3;
    const int ct = xcd * 8 + (i >> 7);      // 0..63
    const int rt = i & 127;                 // 0..127
    const int rowbase = rt * 128, colbase = ct * 128;

    const int wm = wid >> 1, wn = wid & 1;
    const int l15 = lane & 15, q = lane >> 4;
    const int swz = ((q ^ ((l15 >> 1) & 3)) << 4);

    int aoff[4], boff[4];
#pragma unroll
    for (int m = 0; m < 4; ++m) aoff[m] = (wm * 64 + m * 16 + l15) * 64 + swz;
#pragma unroll
    for (int n = 0; n < 4; ++n) boff[n] = (wn * 64 + n * 16 + l15) * 64 + swz;

    unsigned gA[2], gB[2]; int ldso[2];
#pragma unroll
    for (int c = 0; c < 2; ++c) {
        int p = c * 4096 + wid * 1024 + lane * 16;
        int r = p >> 6, sp = (p >> 4) & 3;
        int sl = sp ^ ((r >> 1) & 3);
        gA[c] = (unsigned)(rowbase + r) * 1024u + (unsigned)(sl * 16);
        gB[c] = (unsigned)(colbase + r) * 1024u + (unsigned)(sl * 16);
        ldso[c] = c * 4096 + wid * 1024;    // wave-uniform LDS base (+lane*16 by HW)
    }
    const char* xb = (const char*)xs;
    const char* eb = (const char*)es;

    f32x4 acc[4][4];
#pragma unroll
    for (int m = 0; m < 4; ++m)
#pragma unroll
        for (int n = 0; n < 4; ++n) acc[m][n] = (f32x4){0.f, 0.f, 0.f, 0.f};

#define STAGE(ks_) { const int bb = ((ks_) & 1) << 14; _Pragma("unroll") \
    for (int c = 0; c < 2; ++c) { \
        ldg_lds16(xb + gA[c] + ((ks_) << 6), smem + bb + ldso[c]); \
        ldg_lds16(eb + gB[c] + ((ks_) << 6), smem + bb + 8192 + ldso[c]); } }

    STAGE(0);
    STAGE(1);

#pragma unroll 2
    for (int ks = 0; ks < 16; ++ks) {
        if (ks == 15) { asm volatile("s_waitcnt vmcnt(0)" ::: "memory"); }
        else          { asm volatile("s_waitcnt vmcnt(4)" ::: "memory"); }
        __builtin_amdgcn_s_barrier();
        __builtin_amdgcn_sched_barrier(0);   // keep ds_reads below the barrier
        const char* Ab = smem + ((ks & 1) << 14);
        const char* Bb = Ab + 8192;
        half8 ah[4], bh[4];
#pragma unroll
        for (int n = 0; n < 4; ++n) bh[n] = *(const half8*)(Bb + boff[n]);
#pragma unroll
        for (int m = 0; m < 4; ++m) ah[m] = *(const half8*)(Ab + aoff[m]);
        __builtin_amdgcn_s_setprio(1);
#pragma unroll
        for (int m = 0; m < 4; ++m)
#pragma unroll
            for (int n = 0; n < 4; ++n)
                acc[m][n] = __builtin_amdgcn_mfma_f32_16x16x32_f16(ah[m], bh[n], acc[m][n], 0, 0, 0);
        __builtin_amdgcn_s_setprio(0);
        __builtin_amdgcn_s_barrier();
        if (ks < 14) STAGE(ks + 2);
    }
#undef STAGE

    // ---- epilogue: score = e2 - 2*dot; per-row top-2 over this 128-col tile ----
    const int cb0 = colbase + wn * 64 + l15;
    float e2v[4];
#pragma unroll
    for (int n = 0; n < 4; ++n) e2v[n] = ws[WS_E2 + cb0 + n * 16];

    unsigned long long* mbuf = (unsigned long long*)smem;  // [4][128] transposed
#pragma unroll
    for (int m = 0; m < 4; ++m) {
#pragma unroll
        for (int j = 0; j < 4; ++j) {
            unsigned long long u0 = enc64(fmaf(-2.f, acc[m][0][j], e2v[0]), cb0);
            unsigned long long u1 = enc64(fmaf(-2.f, acc[m][1][j], e2v[1]), cb0 + 16);
            unsigned long long u2 = enc64(fmaf(-2.f, acc[m][2][j], e2v[2]), cb0 + 32);
            unsigned long long u3 = enc64(fmaf(-2.f, acc[m][3][j], e2v[3]), cb0 + 48);
            unsigned long long a1 = u0 < u1 ? u0 : u1, a2 = u0 < u1 ? u1 : u0;
            unsigned long long b1 = u2 < u3 ? u2 : u3, b2 = u2 < u3 ? u3 : u2;
            unsigned long long t1, t2;
            if (a1 < b1) { t1 = a1; t2 = a2 < b1 ? a2 : b1; }
            else         { t1 = b1; t2 = b2 < a1 ? b2 : a1; }
#pragma unroll
            for (int mk = 1; mk <= 8; mk <<= 1) {
                unsigned long long o1 = __shfl_xor(t1, mk);
                unsigned long long o2 = __shfl_xor(t2, mk);
                if (o1 < t1) { t2 = t1 < o2 ? t1 : o2; t1 = o1; }
                else         { t2 = o1 < t2 ? o1 : t2; }
            }
            if (l15 == 0) {
                int rl = wm * 64 + m * 16 + q * 4 + j;
                mbuf[(wn * 2 + 0) * 128 + rl] = t1;
                mbuf[(wn * 2 + 1) * 128 + rl] = t2;
            }
        }
    }
    __syncthreads();
    if (tid < 128) {   // combine wn-halves: [4][128] layout -> 2-way banks (free)
        unsigned long long s0 = mbuf[tid],       s1 = mbuf[128 + tid];
        unsigned long long s2 = mbuf[256 + tid], s3 = mbuf[384 + tid];
        unsigned long long t1, t2;
        if (s0 < s2) { t1 = s0; t2 = s1 < s2 ? s1 : s2; }
        else         { t1 = s2; t2 = s3 < s0 ? s3 : s0; }
        pt1[ct * N_ROWS + rowbase + tid] = t1;
        pt2[ct * N_ROWS + rowbase + tid] = t2;
    }
}

// ====== kernel 2b: merge 64 col-block partials -> global top-4 ids + gap ======
__global__ void merge_kernel(const unsigned long long* __restrict__ pt1,
                             const unsigned long long* __restrict__ pt2,
                             float* __restrict__ ws) {
    int row = blockIdx.x * 256 + threadIdx.x;
    unsigned long long t[4] = {~0ull, ~0ull, ~0ull, ~0ull};
#pragma unroll 4
    for (int cb = 0; cb < 64; ++cb) {
        unsigned long long a = pt1[cb * N_ROWS + row];
        unsigned long long b = pt2[cb * N_ROWS + row];
#pragma unroll
        for (int z = 0; z < 2; ++z) {
            unsigned long long v = z ? b : a;
            if (v < t[3]) {
                t[3] = v;
                if (t[3] < t[2]) { unsigned long long x = t[2]; t[2] = t[3]; t[3] = x;
                    if (t[2] < t[1]) { x = t[1]; t[1] = t[2]; t[2] = x;
                        if (t[1] < t[0]) { x = t[0]; t[0] = t[1]; t[1] = x; } } }
            }
        }
    }
#pragma unroll
    for (int s = 0; s < 4; ++s)
        ((int*)ws)[WS_PI1 + s * N_ROWS + row] = (int)(t[s] & 0x1FFFu);
    ws[WS_GAP + row] = dec64(t[1]) - dec64(t[0]);
}

// ====== kernel 3: assign = gap-gated fp64 refine + gather/quantize/loss/EMA ======
__global__ void assign_kernel(const float* __restrict__ x, const float* __restrict__ embed,
                              float* __restrict__ ws, float* __restrict__ out) {
    int tid = threadIdx.x, wid = tid >> 6, lane = tid & 63;
    int row = blockIdx.x * 4 + wid;                 // one wave per row
    const float* xr = x + row * DIM + lane * 8;
    float4 xv0 = *(const float4*)xr;
    float4 xv1 = *(const float4*)(xr + 4);
    float xv[8] = {xv0.x, xv0.y, xv0.z, xv0.w, xv1.x, xv1.y, xv1.z, xv1.w};

    float gap = ws[WS_GAP + row];
    int besti = ((const int*)ws)[WS_PI1 + row];
    if (gap <= THRGAP) {   // rare (~1% of rows): exact fp64 over 4 candidates
        double bestv = 1e300; besti = 0x7fffffff;
#pragma unroll
        for (int s = 0; s < 4; ++s) {
            int ci = ((const int*)ws)[WS_PI1 + s * N_ROWS + row];
            const float* er = embed + ci * DIM + lane * 8;
            double d = 0.0;
#pragma unroll
            for (int u = 0; u < 8; ++u) {
                double diff = (double)xv[u] - (double)er[u];
                d += diff * diff;
            }
#pragma unroll
            for (int off = 32; off; off >>= 1) d += __shfl_xor(d, off);
            if (d < bestv || (d == bestv && ci < besti)) { bestv = d; besti = ci; }
        }
    }

    const float* er = embed + besti * DIM + lane * 8;
    float4 q0 = *(const float4*)er;
    float4 q1 = *(const float4*)(er + 4);
    float qv[8] = {q0.x, q0.y, q0.z, q0.w, q1.x, q1.y, q1.z, q1.w};
    float st[8], ls = 0.f;
#pragma unroll
    for (int u = 0; u < 8; ++u) {
        float d = qv[u] - xv[u];
        st[u] = xv[u] + d;          // match ref rounding: x + (q - x)
        ls += d * d;
    }
    float* oq = out + OQ + row * DIM + lane * 8;
    *(float4*)oq       = (float4){st[0], st[1], st[2], st[3]};
    *(float4*)(oq + 4) = (float4){st[4], st[5], st[6], st[7]};
#pragma unroll
    for (int off = 32; off; off >>= 1) ls += __shfl_xor(ls, off);
    __shared__ float lsb[4];
    if (lane == 0) {
        lsb[wid] = ls;
        out[OI + row] = (float)besti;
        atomicAdd(ws + WS_BINS + besti, 1.0f);
    }
    // EMA scatter: OA preset to 0.8*avg; add 0.2*x (OA only 4B-aligned -> scalar)
    float* oa = out + OA + besti * DIM + lane * 8;
#pragma unroll
    for (int u = 0; u < 8; ++u) atomicAdd(oa + u, RESIDF * xv[u]);
    __syncthreads();
    if (tid == 0) atomicAdd(ws + WS_LOSS, lsb[0] + lsb[1] + lsb[2] + lsb[3]);
}

// ===== kernel 4: new_cluster_size, total reduction, finalize loss =====
__global__ void cluster_kernel(const float* __restrict__ cs, float* __restrict__ ws,
                               float* __restrict__ out) {
    int k = blockIdx.x * 256 + threadIdx.x;
    float ncs = DECAYF * cs[k] + RESIDF * ws[WS_BINS + k];
    out[OC + k] = ncs;
    float s = ncs;
#pragma unroll
    for (int off = 32; off; off >>= 1) s += __shfl_xor(s, off);
    __shared__ float ls[4];
    int wid = threadIdx.x >> 6, lane = threadIdx.x & 63;
    if (lane == 0) ls[wid] = s;
    __syncthreads();
    if (threadIdx.x == 0) atomicAdd(ws + WS_TOTAL, ls[0] + ls[1] + ls[2] + ls[3]);
    if (k == 0) out[OL] = ws[WS_LOSS] / 8388608.0f;
}

// ===== kernel 5: new_embed = new_embed_avg / laplace-smoothed cluster sizes =====
__global__ void finalize_kernel(const float* __restrict__ ws, float* __restrict__ out) {
    int i = blockIdx.x * 256 + threadIdx.x;
    int base = i * 4;
    int k = base >> 9;
    float total = ws[WS_TOTAL];
    float ncs = out[OC + k];
    float sm = (ncs + EPSF) / (total + (float)KCODES * EPSF) * total;
#pragma unroll
    for (int j = 0; j < 4; ++j) {
        float av = out[OA + base + j];
        out[OE + base + j] = av / sm;
    }
}

extern "C" void kernel_launch(void* const* d_in, const int* in_sizes, int n_in,
                              void* d_out, int out_size, void* d_ws, size_t ws_size,
                              hipStream_t stream) {
    const float* x     = (const float*)d_in[0];
    const float* embed = (const float*)d_in[1];
    const float* cs    = (const float*)d_in[2];
    const float* avg   = (const float*)d_in[3];
    float* out = (float*)d_out;
    float* ws  = (float*)d_ws;

    // fp16/partial scratch inside d_out (each region consumed before its producer's
    // final contents are written):
    //   Xs (16.8MB) in OQ; Es (8.39MB) in OE first half;
    //   pt1 (8.39MB) in OE second half (12B tail spills into OC, rewritten by cluster);
    //   pt2 (8.39MB) in OA (overwritten by avginit AFTER merge consumes it).
    _Float16* xs = (_Float16*)((char*)d_out + (size_t)OQ * 4);
    char* esb = (char*)d_out + (((size_t)OE * 4 + 15) & ~(size_t)15);
    _Float16* es = (_Float16*)esb;
    unsigned long long* pt1 = (unsigned long long*)(esb + (size_t)KCODES * DIM * 2);
    unsigned long long* pt2 =
        (unsigned long long*)((char*)d_out + (((size_t)OA * 4 + 15) & ~(size_t)15));

    hipMemsetAsync((char*)d_ws + WS_BINS * 4, 0, (8192 + 2) * 4, stream);

    convx_kernel  <<<4096, 256, 0, stream>>>(x, xs);
    conve_kernel  <<<2048, 256, 0, stream>>>(embed, es, ws);
    dist_kernel   <<<8192, 256, 0, stream>>>(xs, es, ws, pt1, pt2);
    merge_kernel  <<<64, 256, 0, stream>>>(pt1, pt2, ws);
    avginit_kernel<<<4096, 256, 0, stream>>>(avg, out);
    assign_kernel <<<4096, 256, 0, stream>>>(x, embed, ws, out);
    cluster_kernel<<<32, 256, 0, stream>>>(cs, ws, out);
    finalize_kernel<<<4096, 256, 0, stream>>>(ws, out);
}

// Round 5
// 431.890 us; speedup vs baseline: 1.6429x; 1.3223x over previous
//
#include <hip/hip_runtime.h>

// Problem constants (fixed shapes for this identifier)
#define N_ROWS 16384   // b*n = 4*4096
#define DIM    512
#define KCODES 8192

#define DECAYF 0.8f
#define RESIDF 0.2f
#define EPSF   1e-5f
#define THRGAP 0.15f   // refine-skip threshold (~8 sigma of 1-pass fp16 score noise)

// ---- d_out float offsets (outputs concatenated in return order) ----
#define OQ 0            // quantize_st    [16384,512]  (scratch: Xs fp16)
#define OI 8388608      // ind            [16384]
#define OL 8404992      // commit_loss    [1]
#define OE 8404993      // new_embed      [8192,512]   (scratch: Es fp16 + pt1)
#define OC 12599297     // new_cluster    [8192]
#define OA 12607489     // new_embed_avg  [8192,512]   (scratch: pt2)

// ---- workspace offsets (float-indexed; int arrays alias) ----
#define WS_E2     0                    // [8192] float
#define WS_BINS   8192                 // [8192] int counts (zeroed each call)
#define WS_LOSS   16384                // [1] float
#define WS_TOTAL  16385                // [1] float
#define WS_PI1    16400                // [4][16384] int top-4 candidate idx
#define WS_GAP    (16400+65536)        // [16384] float noisy top1-top2 gap
#define WS_IND    (WS_GAP+16384)       // [16384] int final index
#define WS_OFF    (WS_IND+16384)       // [8192] int exclusive offsets
#define WS_WOFF   (WS_OFF+8192)        // [8192] int working offsets (scatter)
#define WS_SORTED (WS_WOFF+8192)       // [16384] int row ids sorted by code

typedef _Float16 half8 __attribute__((ext_vector_type(8)));
typedef float f32x4 __attribute__((ext_vector_type(4)));

__device__ __forceinline__ void ldg_lds16(const char* g, char* l) {
    __builtin_amdgcn_global_load_lds(
        (const __attribute__((address_space(1))) void*)g,
        (__attribute__((address_space(3))) void*)l, 16, 0, 0);
}

// monotonic (score,idx) -> u64: order-preserving, ties break to smaller idx
__device__ __forceinline__ unsigned long long enc64(float v, int idx) {
    unsigned int b = __float_as_uint(v);
    b ^= (unsigned)((int)b >> 31) | 0x80000000u;
    return ((unsigned long long)b << 13) | (unsigned)idx;
}
__device__ __forceinline__ float dec64(unsigned long long u) {
    unsigned int eb = (unsigned int)(u >> 13);
    unsigned int b = (eb & 0x80000000u) ? (eb ^ 0x80000000u) : ~eb;
    return __uint_as_float(b);
}

// ======= kernel 0a: x (f32) -> Xs fp16 =======
__global__ void convx_kernel(const float* __restrict__ x, _Float16* __restrict__ xs) {
    int i = blockIdx.x * 256 + threadIdx.x;
    int row = i >> 6;
    int c8 = (i & 63) * 8;
    const float4* g = (const float4*)(x + row * DIM + c8);
    float4 v0 = g[0], v1 = g[1];
    float vv[8] = {v0.x, v0.y, v0.z, v0.w, v1.x, v1.y, v1.z, v1.w};
    half8 hv;
#pragma unroll
    for (int j = 0; j < 8; ++j) hv[j] = (_Float16)vv[j];
    *(half8*)(xs + row * DIM + c8) = hv;
}

// ======= kernel 0b: embed -> Es fp16 + e2[k] = sum(embed[k]^2) f32 (fused) =======
__global__ void conve_kernel(const float* __restrict__ e, _Float16* __restrict__ es,
                             float* __restrict__ ws) {
    int i = blockIdx.x * 256 + threadIdx.x;        // one wave per code row
    int row = i >> 6;
    int lane = threadIdx.x & 63;
    int c8 = (i & 63) * 8;
    const float4* g = (const float4*)(e + row * DIM + c8);
    float4 v0 = g[0], v1 = g[1];
    float vv[8] = {v0.x, v0.y, v0.z, v0.w, v1.x, v1.y, v1.z, v1.w};
    half8 hv;
    float s = 0.f;
#pragma unroll
    for (int j = 0; j < 8; ++j) { hv[j] = (_Float16)vv[j]; s += vv[j] * vv[j]; }
    *(half8*)(es + row * DIM + c8) = hv;
#pragma unroll
    for (int off = 32; off; off >>= 1) s += __shfl_xor(s, off);
    if (lane == 0) ws[WS_E2 + row] = s;
}

// ============ kernel 1: 1-pass fp16 MFMA distance GEMM, 128x128 tile ============
// 4 waves (2x2, wave tile 64x64), BK=32 (64B/row), 16 K-steps, dbuf LDS 32KB ->
// 4 blocks/CU. Counted vmcnt(4). Swizzle on 64B rows; staging pre-swizzles the
// GLOBAL source, LDS stays linear (rule 21).
__global__ __launch_bounds__(256, 4) void dist_kernel(
        const _Float16* __restrict__ xs, const _Float16* __restrict__ es,
        const float* __restrict__ ws,
        unsigned long long* __restrict__ pt1, unsigned long long* __restrict__ pt2) {
    __shared__ __align__(16) char smem[32768];

    const int tid = threadIdx.x, wid = tid >> 6, lane = tid & 63;
    const int xcd = blockIdx.x & 7, i = blockIdx.x >> 3;
    const int ct = xcd * 8 + (i >> 7);      // 0..63
    const int rt = i & 127;                 // 0..127
    const int rowbase = rt * 128, colbase = ct * 128;

    const int wm = wid >> 1, wn = wid & 1;
    const int l15 = lane & 15, q = lane >> 4;
    const int swz = ((q ^ ((l15 >> 1) & 3)) << 4);

    int aoff[4], boff[4];
#pragma unroll
    for (int m = 0; m < 4; ++m) aoff[m] = (wm * 64 + m * 16 + l15) * 64 + swz;
#pragma unroll
    for (int n = 0; n < 4; ++n) boff[n] = (wn * 64 + n * 16 + l15) * 64 + swz;

    unsigned gA[2], gB[2]; int ldso[2];
#pragma unroll
    for (int c = 0; c < 2; ++c) {
        int p = c * 4096 + wid * 1024 + lane * 16;
        int r = p >> 6, sp = (p >> 4) & 3;
        int sl = sp ^ ((r >> 1) & 3);
        gA[c] = (unsigned)(rowbase + r) * 1024u + (unsigned)(sl * 16);
        gB[c] = (unsigned)(colbase + r) * 1024u + (unsigned)(sl * 16);
        ldso[c] = c * 4096 + wid * 1024;
    }
    const char* xb = (const char*)xs;
    const char* eb = (const char*)es;

    f32x4 acc[4][4];
#pragma unroll
    for (int m = 0; m < 4; ++m)
#pragma unroll
        for (int n = 0; n < 4; ++n) acc[m][n] = (f32x4){0.f, 0.f, 0.f, 0.f};

#define STAGE(ks_) { const int bb = ((ks_) & 1) << 14; _Pragma("unroll") \
    for (int c = 0; c < 2; ++c) { \
        ldg_lds16(xb + gA[c] + ((ks_) << 6), smem + bb + ldso[c]); \
        ldg_lds16(eb + gB[c] + ((ks_) << 6), smem + bb + 8192 + ldso[c]); } }

    STAGE(0);
    STAGE(1);

#pragma unroll 2
    for (int ks = 0; ks < 16; ++ks) {
        if (ks == 15) { asm volatile("s_waitcnt vmcnt(0)" ::: "memory"); }
        else          { asm volatile("s_waitcnt vmcnt(4)" ::: "memory"); }
        __builtin_amdgcn_s_barrier();
        __builtin_amdgcn_sched_barrier(0);
        const char* Ab = smem + ((ks & 1) << 14);
        const char* Bb = Ab + 8192;
        half8 ah[4], bh[4];
#pragma unroll
        for (int n = 0; n < 4; ++n) bh[n] = *(const half8*)(Bb + boff[n]);
#pragma unroll
        for (int m = 0; m < 4; ++m) ah[m] = *(const half8*)(Ab + aoff[m]);
        __builtin_amdgcn_s_setprio(1);
#pragma unroll
        for (int m = 0; m < 4; ++m)
#pragma unroll
            for (int n = 0; n < 4; ++n)
                acc[m][n] = __builtin_amdgcn_mfma_f32_16x16x32_f16(ah[m], bh[n], acc[m][n], 0, 0, 0);
        __builtin_amdgcn_s_setprio(0);
        __builtin_amdgcn_s_barrier();
        if (ks < 14) STAGE(ks + 2);
    }
#undef STAGE

    // ---- epilogue: score = e2 - 2*dot; per-row top-2 over this 128-col tile ----
    const int cb0 = colbase + wn * 64 + l15;
    float e2v[4];
#pragma unroll
    for (int n = 0; n < 4; ++n) e2v[n] = ws[WS_E2 + cb0 + n * 16];

    unsigned long long* mbuf = (unsigned long long*)smem;  // [4][128] transposed
#pragma unroll
    for (int m = 0; m < 4; ++m) {
#pragma unroll
        for (int j = 0; j < 4; ++j) {
            unsigned long long u0 = enc64(fmaf(-2.f, acc[m][0][j], e2v[0]), cb0);
            unsigned long long u1 = enc64(fmaf(-2.f, acc[m][1][j], e2v[1]), cb0 + 16);
            unsigned long long u2 = enc64(fmaf(-2.f, acc[m][2][j], e2v[2]), cb0 + 32);
            unsigned long long u3 = enc64(fmaf(-2.f, acc[m][3][j], e2v[3]), cb0 + 48);
            unsigned long long a1 = u0 < u1 ? u0 : u1, a2 = u0 < u1 ? u1 : u0;
            unsigned long long b1 = u2 < u3 ? u2 : u3, b2 = u2 < u3 ? u3 : u2;
            unsigned long long t1, t2;
            if (a1 < b1) { t1 = a1; t2 = a2 < b1 ? a2 : b1; }
            else         { t1 = b1; t2 = b2 < a1 ? b2 : a1; }
#pragma unroll
            for (int mk = 1; mk <= 8; mk <<= 1) {
                unsigned long long o1 = __shfl_xor(t1, mk);
                unsigned long long o2 = __shfl_xor(t2, mk);
                if (o1 < t1) { t2 = t1 < o2 ? t1 : o2; t1 = o1; }
                else         { t2 = o1 < t2 ? o1 : t2; }
            }
            if (l15 == 0) {
                int rl = wm * 64 + m * 16 + q * 4 + j;
                mbuf[(wn * 2 + 0) * 128 + rl] = t1;
                mbuf[(wn * 2 + 1) * 128 + rl] = t2;
            }
        }
    }
    __syncthreads();
    if (tid < 128) {
        unsigned long long s0 = mbuf[tid],       s1 = mbuf[128 + tid];
        unsigned long long s2 = mbuf[256 + tid], s3 = mbuf[384 + tid];
        unsigned long long t1, t2;
        if (s0 < s2) { t1 = s0; t2 = s1 < s2 ? s1 : s2; }
        else         { t1 = s2; t2 = s3 < s0 ? s3 : s0; }
        pt1[ct * N_ROWS + rowbase + tid] = t1;
        pt2[ct * N_ROWS + rowbase + tid] = t2;
    }
}

// ====== kernel 2: merge 64 col-block partials -> global top-4 ids + gap ======
__global__ void merge_kernel(const unsigned long long* __restrict__ pt1,
                             const unsigned long long* __restrict__ pt2,
                             float* __restrict__ ws) {
    int row = blockIdx.x * 256 + threadIdx.x;
    unsigned long long t[4] = {~0ull, ~0ull, ~0ull, ~0ull};
#pragma unroll 4
    for (int cb = 0; cb < 64; ++cb) {
        unsigned long long a = pt1[cb * N_ROWS + row];
        unsigned long long b = pt2[cb * N_ROWS + row];
#pragma unroll
        for (int z = 0; z < 2; ++z) {
            unsigned long long v = z ? b : a;
            if (v < t[3]) {
                t[3] = v;
                if (t[3] < t[2]) { unsigned long long x = t[2]; t[2] = t[3]; t[3] = x;
                    if (t[2] < t[1]) { x = t[1]; t[1] = t[2]; t[2] = x;
                        if (t[1] < t[0]) { x = t[0]; t[0] = t[1]; t[1] = x; } } }
            }
        }
    }
#pragma unroll
    for (int s = 0; s < 4; ++s)
        ((int*)ws)[WS_PI1 + s * N_ROWS + row] = (int)(t[s] & 0x1FFFu);
    ws[WS_GAP + row] = dec64(t[1]) - dec64(t[0]);
}

// ====== kernel 3: assign = gap-gated fp64 refine + quantize + loss + bins ======
__global__ void assign_kernel(const float* __restrict__ x, const float* __restrict__ embed,
                              float* __restrict__ ws, float* __restrict__ out) {
    int tid = threadIdx.x, wid = tid >> 6, lane = tid & 63;
    int row = blockIdx.x * 4 + wid;                 // one wave per row
    const float* xr = x + row * DIM + lane * 8;
    float4 xv0 = *(const float4*)xr;
    float4 xv1 = *(const float4*)(xr + 4);
    float xv[8] = {xv0.x, xv0.y, xv0.z, xv0.w, xv1.x, xv1.y, xv1.z, xv1.w};

    float gap = ws[WS_GAP + row];
    int besti = ((const int*)ws)[WS_PI1 + row];
    if (gap <= THRGAP) {   // rare: exact fp64 over 4 candidates
        double bestv = 1e300; besti = 0x7fffffff;
#pragma unroll
        for (int s = 0; s < 4; ++s) {
            int ci = ((const int*)ws)[WS_PI1 + s * N_ROWS + row];
            const float* er = embed + ci * DIM + lane * 8;
            double d = 0.0;
#pragma unroll
            for (int u = 0; u < 8; ++u) {
                double diff = (double)xv[u] - (double)er[u];
                d += diff * diff;
            }
#pragma unroll
            for (int off = 32; off; off >>= 1) d += __shfl_xor(d, off);
            if (d < bestv || (d == bestv && ci < besti)) { bestv = d; besti = ci; }
        }
    }

    const float* er = embed + besti * DIM + lane * 8;
    float4 q0 = *(const float4*)er;
    float4 q1 = *(const float4*)(er + 4);
    float qv[8] = {q0.x, q0.y, q0.z, q0.w, q1.x, q1.y, q1.z, q1.w};
    float st[8], ls = 0.f;
#pragma unroll
    for (int u = 0; u < 8; ++u) {
        float d = qv[u] - xv[u];
        st[u] = xv[u] + d;          // match ref rounding: x + (q - x)
        ls += d * d;
    }
    float* oq = out + OQ + row * DIM + lane * 8;
    *(float4*)oq       = (float4){st[0], st[1], st[2], st[3]};
    *(float4*)(oq + 4) = (float4){st[4], st[5], st[6], st[7]};
#pragma unroll
    for (int off = 32; off; off >>= 1) ls += __shfl_xor(ls, off);
    __shared__ float lsb[4];
    if (lane == 0) {
        lsb[wid] = ls;
        out[OI + row] = (float)besti;
        ((int*)ws)[WS_IND + row] = besti;
        atomicAdd((int*)ws + WS_BINS + besti, 1);
    }
    __syncthreads();
    if (tid == 0) atomicAdd(ws + WS_LOSS, lsb[0] + lsb[1] + lsb[2] + lsb[3]);
}

// ===== kernel 4: new_cluster_size + total + finalize loss =====
__global__ void cluster_kernel(const float* __restrict__ cs, float* __restrict__ ws,
                               float* __restrict__ out) {
    int k = blockIdx.x * 256 + threadIdx.x;
    float ncs = DECAYF * cs[k] + RESIDF * (float)((const int*)ws)[WS_BINS + k];
    out[OC + k] = ncs;
    float s = ncs;
#pragma unroll
    for (int off = 32; off; off >>= 1) s += __shfl_xor(s, off);
    __shared__ float ls[4];
    int wid = threadIdx.x >> 6, lane = threadIdx.x & 63;
    if (lane == 0) ls[wid] = s;
    __syncthreads();
    if (threadIdx.x == 0) atomicAdd(ws + WS_TOTAL, ls[0] + ls[1] + ls[2] + ls[3]);
    if (k == 0) out[OL] = ws[WS_LOSS] / 8388608.0f;
}

// ===== kernel 5: exclusive prefix scan of bins -> offsets (single block) =====
__global__ void scan_kernel(float* __restrict__ ws) {
    __shared__ int lds[256];
    int tid = threadIdx.x;
    const int* bins = (const int*)ws + WS_BINS;
    int* off  = (int*)ws + WS_OFF;
    int* woff = (int*)ws + WS_WOFF;
    int local[32], s = 0;
    int base = tid * 32;
#pragma unroll
    for (int j = 0; j < 32; ++j) { local[j] = bins[base + j]; s += local[j]; }
    lds[tid] = s;
    __syncthreads();
    // Hillis-Steele inclusive scan over 256 partials
    for (int o = 1; o < 256; o <<= 1) {
        int v = (tid >= o) ? lds[tid - o] : 0;
        __syncthreads();
        lds[tid] += v;
        __syncthreads();
    }
    int run = lds[tid] - s;   // exclusive
#pragma unroll
    for (int j = 0; j < 32; ++j) {
        off[base + j] = run; woff[base + j] = run;
        run += local[j];
    }
}

// ===== kernel 6: scatter row ids into code-sorted order =====
__global__ void scatter_kernel(float* __restrict__ ws) {
    int row = blockIdx.x * 256 + threadIdx.x;
    int ind = ((const int*)ws)[WS_IND + row];
    int pos = atomicAdd((int*)ws + WS_WOFF + ind, 1);
    ((int*)ws)[WS_SORTED + pos] = row;
}

// ===== kernel 7: segmented EMA sum + smoothed divide (one wave per code) =====
__global__ void ema_kernel(const float* __restrict__ x, const float* __restrict__ avg,
                           const float* __restrict__ ws, float* __restrict__ out) {
    int tid = threadIdx.x, wid = tid >> 6, lane = tid & 63;
    int k = blockIdx.x * 4 + wid;
    int cnt   = ((const int*)ws)[WS_BINS + k];
    int start = ((const int*)ws)[WS_OFF + k];
    const int c8 = lane * 8;
    float sum[8] = {0.f, 0.f, 0.f, 0.f, 0.f, 0.f, 0.f, 0.f};
    for (int c = 0; c < cnt; ++c) {
        int row = ((const int*)ws)[WS_SORTED + start + c];
        const float* xr = x + row * DIM + c8;
        float4 v0 = *(const float4*)xr;
        float4 v1 = *(const float4*)(xr + 4);
        sum[0] += v0.x; sum[1] += v0.y; sum[2] += v0.z; sum[3] += v0.w;
        sum[4] += v1.x; sum[5] += v1.y; sum[6] += v1.z; sum[7] += v1.w;
    }
    const float* ar = avg + k * DIM + c8;
    float4 a0 = *(const float4*)ar;
    float4 a1 = *(const float4*)(ar + 4);
    float av[8] = {a0.x, a0.y, a0.z, a0.w, a1.x, a1.y, a1.z, a1.w};
    float total = ws[WS_TOTAL];
    float ncs = out[OC + k];
    float sm = (ncs + EPSF) / (total + (float)KCODES * EPSF) * total;
    float* oa = out + OA + k * DIM + c8;   // 4B-aligned regions -> scalar stores
    float* oe = out + OE + k * DIM + c8;
#pragma unroll
    for (int u = 0; u < 8; ++u) {
        float na = DECAYF * av[u] + RESIDF * sum[u];
        oa[u] = na;
        oe[u] = na / sm;
    }
}

extern "C" void kernel_launch(void* const* d_in, const int* in_sizes, int n_in,
                              void* d_out, int out_size, void* d_ws, size_t ws_size,
                              hipStream_t stream) {
    const float* x     = (const float*)d_in[0];
    const float* embed = (const float*)d_in[1];
    const float* cs    = (const float*)d_in[2];
    const float* avg   = (const float*)d_in[3];
    float* out = (float*)d_out;
    float* ws  = (float*)d_ws;

    // fp16/partial scratch inside d_out (each region consumed before final write):
    //   Xs (16.8MB) in OQ; Es (8.39MB) in OE first half;
    //   pt1 (8.39MB) in OE second half; pt2 (8.39MB) in OA.
    //   merge consumes pt1/pt2 before ema writes OE/OA.
    _Float16* xs = (_Float16*)((char*)d_out + (size_t)OQ * 4);
    char* esb = (char*)d_out + (((size_t)OE * 4 + 15) & ~(size_t)15);
    _Float16* es = (_Float16*)esb;
    unsigned long long* pt1 = (unsigned long long*)(esb + (size_t)KCODES * DIM * 2);
    unsigned long long* pt2 =
        (unsigned long long*)((char*)d_out + (((size_t)OA * 4 + 15) & ~(size_t)15));

    // zero bins + loss + total each call
    hipMemsetAsync((char*)d_ws + WS_BINS * 4, 0, (8192 + 2) * 4, stream);

    convx_kernel  <<<4096, 256, 0, stream>>>(x, xs);
    conve_kernel  <<<2048, 256, 0, stream>>>(embed, es, ws);
    dist_kernel   <<<8192, 256, 0, stream>>>(xs, es, ws, pt1, pt2);
    merge_kernel  <<<64, 256, 0, stream>>>(pt1, pt2, ws);
    assign_kernel <<<4096, 256, 0, stream>>>(x, embed, ws, out);
    cluster_kernel<<<32, 256, 0, stream>>>(cs, ws, out);
    scan_kernel   <<<1, 256, 0, stream>>>(ws);
    scatter_kernel<<<64, 256, 0, stream>>>(ws);
    ema_kernel    <<<2048, 256, 0, stream>>>(x, avg, ws, out);
}

// Round 6
// 419.585 us; speedup vs baseline: 1.6911x; 1.0293x over previous
//
#include <hip/hip_runtime.h>

// Problem constants (fixed shapes for this identifier)
#define N_ROWS 16384   // b*n = 4*4096
#define DIM    512
#define KCODES 8192

#define DECAYF 0.8f
#define RESIDF 0.2f
#define EPSF   1e-5f
#define THRGAP 0.15f   // refine-skip threshold (~8 sigma of 1-pass fp16 score noise)
#define NSPLIT 8       // col splits (1024 cols each), one per XCD

// ---- d_out float offsets (outputs concatenated in return order) ----
#define OQ 0            // quantize_st    [16384,512]  (scratch: Xs fp16)
#define OI 8388608      // ind            [16384]
#define OL 8404992      // commit_loss    [1]
#define OE 8404993      // new_embed      [8192,512]   (scratch: Es fp16 + pt1)
#define OC 12599297     // new_cluster    [8192]
#define OA 12607489     // new_embed_avg  [8192,512]   (scratch: pt2)

// ---- workspace offsets (float-indexed; int arrays alias) ----
#define WS_E2     0                    // [8192] float
#define WS_BINS   8192                 // [8192] int counts (zeroed each call)
#define WS_LOSS   16384                // [1] float
#define WS_TOTAL  16385                // [1] float
#define WS_PI1    16400                // [4][16384] int top-4 candidate idx
#define WS_GAP    (16400+65536)        // [16384] float noisy top1-top2 gap
#define WS_IND    (WS_GAP+16384)       // [16384] int final index
#define WS_OFF    (WS_IND+16384)       // [8192] int exclusive offsets
#define WS_WOFF   (WS_OFF+8192)        // [8192] int working offsets (scatter)
#define WS_SORTED (WS_WOFF+8192)       // [16384] int row ids sorted by code

typedef _Float16 half8 __attribute__((ext_vector_type(8)));
typedef float f32x4 __attribute__((ext_vector_type(4)));

__device__ __forceinline__ void ldg_lds16(const char* g, char* l) {
    __builtin_amdgcn_global_load_lds(
        (const __attribute__((address_space(1))) void*)g,
        (__attribute__((address_space(3))) void*)l, 16, 0, 0);
}

// monotonic (score,idx) -> u64: order-preserving, ties break to smaller idx
__device__ __forceinline__ unsigned long long enc64(float v, unsigned idx) {
    unsigned int b = __float_as_uint(v);
    b ^= (unsigned)((int)b >> 31) | 0x80000000u;
    return ((unsigned long long)b << 13) | idx;
}
__device__ __forceinline__ float dec64(unsigned long long u) {
    unsigned int eb = (unsigned int)(u >> 13);
    unsigned int b = (eb & 0x80000000u) ? (eb ^ 0x80000000u) : ~eb;
    return __uint_as_float(b);
}

// ======= kernel 0: fused x->Xs fp16 (blocks 0..4095) and embed->Es fp16 + e2 =======
__global__ void convxe_kernel(const float* __restrict__ x, const float* __restrict__ e,
                              _Float16* __restrict__ xs, _Float16* __restrict__ es,
                              float* __restrict__ ws) {
    if (blockIdx.x < 4096) {
        int i = blockIdx.x * 256 + threadIdx.x;
        int row = i >> 6;
        int c8 = (i & 63) * 8;
        const float4* g = (const float4*)(x + row * DIM + c8);
        float4 v0 = g[0], v1 = g[1];
        float vv[8] = {v0.x, v0.y, v0.z, v0.w, v1.x, v1.y, v1.z, v1.w};
        half8 hv;
#pragma unroll
        for (int j = 0; j < 8; ++j) hv[j] = (_Float16)vv[j];
        *(half8*)(xs + row * DIM + c8) = hv;
    } else {
        int i = (blockIdx.x - 4096) * 256 + threadIdx.x;   // one wave per code row
        int row = i >> 6;
        int lane = threadIdx.x & 63;
        int c8 = (i & 63) * 8;
        const float4* g = (const float4*)(e + row * DIM + c8);
        float4 v0 = g[0], v1 = g[1];
        float vv[8] = {v0.x, v0.y, v0.z, v0.w, v1.x, v1.y, v1.z, v1.w};
        half8 hv;
        float s = 0.f;
#pragma unroll
        for (int j = 0; j < 8; ++j) { hv[j] = (_Float16)vv[j]; s += vv[j] * vv[j]; }
        *(half8*)(es + row * DIM + c8) = hv;
#pragma unroll
        for (int off = 32; off; off >>= 1) s += __shfl_xor(s, off);
        if (lane == 0) ws[WS_E2 + row] = s;
    }
}

// ============ kernel 1: 1-pass fp16 MFMA distance GEMM, 128-row x 1024-col sweep ============
// Grid 1024 = 128 rt x 8 splits (split == XCD -> 1MB B-slice L2-resident). Per block:
// 8 windows of 128 cols; verified K-loop (BK=32, dbuf 32KB, vmcnt(4), swizzle rule-21)
// runs per window; each window's acc folds into per-row running top-2 registers via
// branch-free min/med3 insert. Cross-lane butterfly happens ONCE per block (not per tile).
__global__ __launch_bounds__(256, 2) void dist_kernel(
        const _Float16* __restrict__ xs, const _Float16* __restrict__ es,
        const float* __restrict__ ws,
        unsigned long long* __restrict__ pt1, unsigned long long* __restrict__ pt2) {
    __shared__ __align__(16) char smem[32768];

    const int tid = threadIdx.x, wid = tid >> 6, lane = tid & 63;
    const int split = blockIdx.x & 7;       // = XCD
    const int rt    = blockIdx.x >> 3;      // 0..127
    const int rowbase = rt * 128, colsplit = split * 1024;

    const int wm = wid >> 1, wn = wid & 1;
    const int l15 = lane & 15, q = lane >> 4;
    const int swz = ((q ^ ((l15 >> 1) & 3)) << 4);

    int aoff[4], boff[4];
#pragma unroll
    for (int m = 0; m < 4; ++m) aoff[m] = (wm * 64 + m * 16 + l15) * 64 + swz;
#pragma unroll
    for (int n = 0; n < 4; ++n) boff[n] = (wn * 64 + n * 16 + l15) * 64 + swz;

    unsigned gA[2], gB[2]; int ldso[2];
#pragma unroll
    for (int c = 0; c < 2; ++c) {
        int p = c * 4096 + wid * 1024 + lane * 16;
        int r = p >> 6, sp = (p >> 4) & 3;
        int sl = sp ^ ((r >> 1) & 3);
        gA[c] = (unsigned)(rowbase + r) * 1024u + (unsigned)(sl * 16);
        gB[c] = (unsigned)(colsplit + r) * 1024u + (unsigned)(sl * 16);
        ldso[c] = c * 4096 + wid * 1024;
    }
    const char* xb = (const char*)xs;
    const char* eb = (const char*)es;

    // running per-row top-2: b1<=b2, cp = c1 | (c2<<16); rows r = m*4+j
    float b1[16], b2[16]; unsigned cp[16];
#pragma unroll
    for (int r = 0; r < 16; ++r) { b1[r] = 3.4e38f; b2[r] = 3.4e38f; cp[r] = 0xFFFFFFFFu; }

    f32x4 acc[4][4];
#pragma unroll
    for (int m = 0; m < 4; ++m)
#pragma unroll
        for (int n = 0; n < 4; ++n) acc[m][n] = (f32x4){0.f, 0.f, 0.f, 0.f};

    // STAGE(gi): gi = w*16 + ks; A repeats per window, B advances by 128KB per window
#define STAGE(gi_) { const int bb = ((gi_) & 1) << 14; \
    const unsigned koff = ((unsigned)((gi_) & 15)) << 6; \
    const unsigned woff = ((unsigned)((gi_) >> 4)) << 17; \
    _Pragma("unroll") \
    for (int c = 0; c < 2; ++c) { \
        ldg_lds16(xb + gA[c] + koff, smem + bb + ldso[c]); \
        ldg_lds16(eb + gB[c] + woff + koff, smem + bb + 8192 + ldso[c]); } }

    STAGE(0);
    STAGE(1);

    for (int w = 0; w < 8; ++w) {
        float e2v[4];
#pragma unroll
        for (int n = 0; n < 4; ++n)
            e2v[n] = ws[WS_E2 + colsplit + w * 128 + wn * 64 + n * 16 + l15];

#pragma unroll 2
        for (int ks = 0; ks < 16; ++ks) {
            const int gi = (w << 4) + ks;
            if (gi == 127) { asm volatile("s_waitcnt vmcnt(0)" ::: "memory"); }
            else           { asm volatile("s_waitcnt vmcnt(4)" ::: "memory"); }
            __builtin_amdgcn_s_barrier();
            __builtin_amdgcn_sched_barrier(0);
            const char* Ab = smem + ((ks & 1) << 14);
            const char* Bb = Ab + 8192;
            half8 ah[4], bh[4];
#pragma unroll
            for (int n = 0; n < 4; ++n) bh[n] = *(const half8*)(Bb + boff[n]);
#pragma unroll
            for (int m = 0; m < 4; ++m) ah[m] = *(const half8*)(Ab + aoff[m]);
            __builtin_amdgcn_s_setprio(1);
#pragma unroll
            for (int m = 0; m < 4; ++m)
#pragma unroll
                for (int n = 0; n < 4; ++n)
                    acc[m][n] = __builtin_amdgcn_mfma_f32_16x16x32_f16(ah[m], bh[n], acc[m][n], 0, 0, 0);
            __builtin_amdgcn_s_setprio(0);
            __builtin_amdgcn_s_barrier();
            if (gi < 126) STAGE(gi + 2);
        }

        // fold window w into running top-2 (cols ascend -> first-occurrence ties kept)
        const unsigned cw = (unsigned)(colsplit + w * 128 + wn * 64 + l15);
#pragma unroll
        for (int m = 0; m < 4; ++m)
#pragma unroll
            for (int j = 0; j < 4; ++j) {
                const int r = m * 4 + j;
#pragma unroll
                for (int n = 0; n < 4; ++n) {
                    float v = fmaf(-2.f, acc[m][n][j], e2v[n]);
                    unsigned c = cw + n * 16;
                    bool lt1 = v < b1[r], lt2 = v < b2[r];
                    float nb2 = fminf(fmaxf(v, b1[r]), b2[r]);   // median
                    b1[r] = fminf(v, b1[r]);
                    unsigned pA = (cp[r] << 16) | c;              // new top1
                    unsigned pB = (cp[r] & 0xFFFFu) | (c << 16);  // new top2
                    cp[r] = lt1 ? pA : (lt2 ? pB : cp[r]);
                    b2[r] = nb2;
                    acc[m][n][j] = 0.f;                           // reset for next window
                }
            }
    }
#undef STAGE

    // ---- once per block: lexicographic (value, idx) butterfly over the 16 col-lanes ----
#pragma unroll
    for (int mask = 1; mask <= 8; mask <<= 1) {
#pragma unroll
        for (int r = 0; r < 16; ++r) {
            float o1 = __shfl_xor(b1[r], mask);
            float o2 = __shfl_xor(b2[r], mask);
            unsigned ocp = __shfl_xor(cp[r], mask);
            unsigned c1 = cp[r] & 0xFFFFu, c2 = cp[r] >> 16;
            unsigned p1 = ocp & 0xFFFFu,   p2 = ocp >> 16;
            bool lt = (o1 < b1[r]) || (o1 == b1[r] && p1 < c1);
            float n1v, n2v; unsigned n1c, n2c;
            if (lt) {
                n1v = o1; n1c = p1;
                bool t = (b1[r] < o2) || (b1[r] == o2 && c1 < p2);
                n2v = t ? b1[r] : o2; n2c = t ? c1 : p2;
            } else {
                n1v = b1[r]; n1c = c1;
                bool t = (o1 < b2[r]) || (o1 == b2[r] && p1 < c2);
                n2v = t ? o1 : b2[r]; n2c = t ? p1 : c2;
            }
            b1[r] = n1v; b2[r] = n2v; cp[r] = n1c | (n2c << 16);
        }
    }

    unsigned long long* mbuf = (unsigned long long*)smem;  // [4][128]
    if (l15 == 0) {
#pragma unroll
        for (int m = 0; m < 4; ++m)
#pragma unroll
            for (int j = 0; j < 4; ++j) {
                int row = wm * 64 + m * 16 + q * 4 + j;
                int r = m * 4 + j;
                mbuf[(wn * 2 + 0) * 128 + row] = enc64(b1[r], cp[r] & 0xFFFFu);
                mbuf[(wn * 2 + 1) * 128 + row] = enc64(b2[r], cp[r] >> 16);
            }
    }
    __syncthreads();
    if (tid < 128) {   // combine wn-halves -> per-(row, split) top-2
        unsigned long long s0 = mbuf[tid],       s1 = mbuf[128 + tid];
        unsigned long long s2 = mbuf[256 + tid], s3 = mbuf[384 + tid];
        unsigned long long t1, t2;
        if (s0 < s2) { t1 = s0; t2 = s1 < s2 ? s1 : s2; }
        else         { t1 = s2; t2 = s3 < s0 ? s3 : s0; }
        pt1[split * N_ROWS + rowbase + tid] = t1;
        pt2[split * N_ROWS + rowbase + tid] = t2;
    }
}

// ====== kernel 2: merge 8 split partials -> global top-4 ids + gap ======
__global__ void merge_kernel(const unsigned long long* __restrict__ pt1,
                             const unsigned long long* __restrict__ pt2,
                             float* __restrict__ ws) {
    int row = blockIdx.x * 256 + threadIdx.x;
    unsigned long long t[4] = {~0ull, ~0ull, ~0ull, ~0ull};
#pragma unroll
    for (int cb = 0; cb < NSPLIT; ++cb) {
        unsigned long long a = pt1[cb * N_ROWS + row];
        unsigned long long b = pt2[cb * N_ROWS + row];
#pragma unroll
        for (int z = 0; z < 2; ++z) {
            unsigned long long v = z ? b : a;
            if (v < t[3]) {
                t[3] = v;
                if (t[3] < t[2]) { unsigned long long x = t[2]; t[2] = t[3]; t[3] = x;
                    if (t[2] < t[1]) { x = t[1]; t[1] = t[2]; t[2] = x;
                        if (t[1] < t[0]) { x = t[0]; t[0] = t[1]; t[1] = x; } } }
            }
        }
    }
#pragma unroll
    for (int s = 0; s < 4; ++s)
        ((int*)ws)[WS_PI1 + s * N_ROWS + row] = (int)(t[s] & 0x1FFFu);
    ws[WS_GAP + row] = dec64(t[1]) - dec64(t[0]);
}

// ====== kernel 3: assign = gap-gated fp64 refine + quantize + loss + bins ======
__global__ void assign_kernel(const float* __restrict__ x, const float* __restrict__ embed,
                              float* __restrict__ ws, float* __restrict__ out) {
    int tid = threadIdx.x, wid = tid >> 6, lane = tid & 63;
    int row = blockIdx.x * 4 + wid;                 // one wave per row
    const float* xr = x + row * DIM + lane * 8;
    float4 xv0 = *(const float4*)xr;
    float4 xv1 = *(const float4*)(xr + 4);
    float xv[8] = {xv0.x, xv0.y, xv0.z, xv0.w, xv1.x, xv1.y, xv1.z, xv1.w};

    float gap = ws[WS_GAP + row];
    int besti = ((const int*)ws)[WS_PI1 + row];
    if (gap <= THRGAP) {   // rare: exact fp64 over 4 candidates
        double bestv = 1e300; besti = 0x7fffffff;
#pragma unroll
        for (int s = 0; s < 4; ++s) {
            int ci = ((const int*)ws)[WS_PI1 + s * N_ROWS + row];
            const float* er = embed + ci * DIM + lane * 8;
            double d = 0.0;
#pragma unroll
            for (int u = 0; u < 8; ++u) {
                double diff = (double)xv[u] - (double)er[u];
                d += diff * diff;
            }
#pragma unroll
            for (int off = 32; off; off >>= 1) d += __shfl_xor(d, off);
            if (d < bestv || (d == bestv && ci < besti)) { bestv = d; besti = ci; }
        }
    }

    const float* er = embed + besti * DIM + lane * 8;
    float4 q0 = *(const float4*)er;
    float4 q1 = *(const float4*)(er + 4);
    float qv[8] = {q0.x, q0.y, q0.z, q0.w, q1.x, q1.y, q1.z, q1.w};
    float st[8], ls = 0.f;
#pragma unroll
    for (int u = 0; u < 8; ++u) {
        float d = qv[u] - xv[u];
        st[u] = xv[u] + d;          // match ref rounding: x + (q - x)
        ls += d * d;
    }
    float* oq = out + OQ + row * DIM + lane * 8;
    *(float4*)oq       = (float4){st[0], st[1], st[2], st[3]};
    *(float4*)(oq + 4) = (float4){st[4], st[5], st[6], st[7]};
#pragma unroll
    for (int off = 32; off; off >>= 1) ls += __shfl_xor(ls, off);
    __shared__ float lsb[4];
    if (lane == 0) {
        lsb[wid] = ls;
        out[OI + row] = (float)besti;
        ((int*)ws)[WS_IND + row] = besti;
        atomicAdd((int*)ws + WS_BINS + besti, 1);
    }
    __syncthreads();
    if (tid == 0) atomicAdd(ws + WS_LOSS, lsb[0] + lsb[1] + lsb[2] + lsb[3]);
}

// ===== kernel 4: fused cluster + scan (single block): ncs, total, loss, offsets =====
__global__ void scan_kernel(const float* __restrict__ cs, float* __restrict__ ws,
                            float* __restrict__ out) {
    __shared__ int lds[256];
    __shared__ float fl[256];
    int tid = threadIdx.x;
    const int* bins = (const int*)ws + WS_BINS;
    int* off  = (int*)ws + WS_OFF;
    int* woff = (int*)ws + WS_WOFF;
    int base = tid * 32;
    int local[32], s = 0; float sn = 0.f;
#pragma unroll
    for (int j = 0; j < 32; ++j) {
        int b = bins[base + j];
        local[j] = b; s += b;
        float ncs = DECAYF * cs[base + j] + RESIDF * (float)b;
        out[OC + base + j] = ncs;
        sn += ncs;
    }
    lds[tid] = s; fl[tid] = sn;
    __syncthreads();
    for (int o = 1; o < 256; o <<= 1) {   // Hillis-Steele inclusive scan + float total
        int v = (tid >= o) ? lds[tid - o] : 0;
        float f = (tid >= o) ? fl[tid - o] : 0.f;
        __syncthreads();
        lds[tid] += v; fl[tid] += f;
        __syncthreads();
    }
    int run = lds[tid] - s;   // exclusive
#pragma unroll
    for (int j = 0; j < 32; ++j) {
        off[base + j] = run; woff[base + j] = run;
        run += local[j];
    }
    if (tid == 0) {
        ws[WS_TOTAL] = fl[255];
        out[OL] = ws[WS_LOSS] / 8388608.0f;
    }
}

// ===== kernel 5: scatter row ids into code-sorted order =====
__global__ void scatter_kernel(float* __restrict__ ws) {
    int row = blockIdx.x * 256 + threadIdx.x;
    int ind = ((const int*)ws)[WS_IND + row];
    int pos = atomicAdd((int*)ws + WS_WOFF + ind, 1);
    ((int*)ws)[WS_SORTED + pos] = row;
}

// ===== kernel 6: segmented EMA sum + smoothed divide (one wave per code) =====
__global__ void ema_kernel(const float* __restrict__ x, const float* __restrict__ avg,
                           const float* __restrict__ ws, float* __restrict__ out) {
    int tid = threadIdx.x, wid = tid >> 6, lane = tid & 63;
    int k = blockIdx.x * 4 + wid;
    int cnt   = ((const int*)ws)[WS_BINS + k];
    int start = ((const int*)ws)[WS_OFF + k];
    const int c8 = lane * 8;
    float sum[8] = {0.f, 0.f, 0.f, 0.f, 0.f, 0.f, 0.f, 0.f};
    for (int c = 0; c < cnt; ++c) {
        int row = ((const int*)ws)[WS_SORTED + start + c];
        const float* xr = x + row * DIM + c8;
        float4 v0 = *(const float4*)xr;
        float4 v1 = *(const float4*)(xr + 4);
        sum[0] += v0.x; sum[1] += v0.y; sum[2] += v0.z; sum[3] += v0.w;
        sum[4] += v1.x; sum[5] += v1.y; sum[6] += v1.z; sum[7] += v1.w;
    }
    const float* ar = avg + k * DIM + c8;
    float4 a0 = *(const float4*)ar;
    float4 a1 = *(const float4*)(ar + 4);
    float av[8] = {a0.x, a0.y, a0.z, a0.w, a1.x, a1.y, a1.z, a1.w};
    float total = ws[WS_TOTAL];
    float ncs = out[OC + k];
    float sm = (ncs + EPSF) / (total + (float)KCODES * EPSF) * total;
    float* oa = out + OA + k * DIM + c8;   // 4B-aligned regions -> scalar stores
    float* oe = out + OE + k * DIM + c8;
#pragma unroll
    for (int u = 0; u < 8; ++u) {
        float na = DECAYF * av[u] + RESIDF * sum[u];
        oa[u] = na;
        oe[u] = na / sm;
    }
}

extern "C" void kernel_launch(void* const* d_in, const int* in_sizes, int n_in,
                              void* d_out, int out_size, void* d_ws, size_t ws_size,
                              hipStream_t stream) {
    const float* x     = (const float*)d_in[0];
    const float* embed = (const float*)d_in[1];
    const float* cs    = (const float*)d_in[2];
    const float* avg   = (const float*)d_in[3];
    float* out = (float*)d_out;
    float* ws  = (float*)d_ws;

    // fp16/partial scratch inside d_out (each region consumed before final write):
    //   Xs (16.8MB) in OQ; Es (8.39MB) in OE first half; pt1 (1MB) after Es;
    //   pt2 (1MB) in OA. merge consumes pt1/pt2 before ema writes OE/OA.
    _Float16* xs = (_Float16*)((char*)d_out + (size_t)OQ * 4);
    char* esb = (char*)d_out + (((size_t)OE * 4 + 15) & ~(size_t)15);
    _Float16* es = (_Float16*)esb;
    unsigned long long* pt1 = (unsigned long long*)(esb + (size_t)KCODES * DIM * 2);
    unsigned long long* pt2 =
        (unsigned long long*)((char*)d_out + (((size_t)OA * 4 + 15) & ~(size_t)15));

    // zero bins + loss + total each call
    hipMemsetAsync((char*)d_ws + WS_BINS * 4, 0, (8192 + 2) * 4, stream);

    convxe_kernel <<<6144, 256, 0, stream>>>(x, embed, xs, es, ws);
    dist_kernel   <<<1024, 256, 0, stream>>>(xs, es, ws, pt1, pt2);
    merge_kernel  <<<N_ROWS / 256, 256, 0, stream>>>(pt1, pt2, ws);
    assign_kernel <<<N_ROWS / 4, 256, 0, stream>>>(x, embed, ws, out);
    scan_kernel   <<<1, 256, 0, stream>>>(cs, ws, out);
    scatter_kernel<<<N_ROWS / 256, 256, 0, stream>>>(ws);
    ema_kernel    <<<KCODES / 4, 256, 0, stream>>>(x, avg, ws, out);
}